// Round 10
// baseline (748.385 us; speedup 1.0000x reference)
//
#include <hip/hip_runtime.h>
#include <math.h>

#define B_ 64
#define L_ 512
#define C_ 256
#define H_ 4
#define LAY 3
#define NEGV -1e9f

#define GF_BIAS  1
#define GF_RELU  2
#define GF_OBF16 4

typedef __attribute__((ext_vector_type(8))) short short8;
typedef __attribute__((ext_vector_type(4))) short short4v;
typedef __attribute__((ext_vector_type(4))) float floatx4;

static __device__ __forceinline__ float sigmoidf_(float x) { return 1.f / (1.f + expf(-x)); }

static __device__ __forceinline__ short f2bf(float f) {
    unsigned x = __float_as_uint(f);
    x += 0x7fffu + ((x >> 16) & 1u);       // round-to-nearest-even to bf16
    return (short)(x >> 16);
}
static __device__ __forceinline__ float bf2f(short s) {
    return __uint_as_float(((unsigned)(unsigned short)s) << 16);
}

// XCD-aligned token swizzle for elementwise consumers (matches GEMM rb%8 = XCD).
static __device__ __forceinline__ int tok_swizzle(int blk) {
    int c8 = blk & 7, i = blk >> 3;
    return (c8 + 8 * (i >> 5)) * 128 + (i & 31) * 4;
}

static __device__ __forceinline__ void gl_lds16(const short* g, short* l) {
    __builtin_amdgcn_global_load_lds(
        (const __attribute__((address_space(1))) unsigned int*)g,
        (__attribute__((address_space(3))) unsigned int*)l, 16, 0, 0);
}

// ---------------- mask / logical-position scan + pos_of_logical ----------------
__global__ void scan_kernel(const int* __restrict__ x, int* __restrict__ mask,
                            int* __restrict__ logical, int* __restrict__ pol,
                            int* __restrict__ nvalid) {
    int b = blockIdx.x, t = threadIdx.x;
    __shared__ int s[L_];
    int m = (x[b * L_ + t] != 0) ? 1 : 0;
    s[t] = m;
    __syncthreads();
    for (int off = 1; off < L_; off <<= 1) {
        int v = (t >= off) ? s[t - off] : 0;
        __syncthreads();
        s[t] += v;
        __syncthreads();
    }
    int cum = s[t];
    int lg = cum - 1; if (lg < 0) lg = 0;
    mask[b * L_ + t] = m;
    logical[b * L_ + t] = lg;
    if (m) pol[b * L_ + lg] = t;
    if (t == L_ - 1) nvalid[b] = cum;
}

// ---------------- h = (emb[x] + pos*mf)*mf  (fp32 + bf16 copies) ----------------
__global__ void embed_kernel(const int* __restrict__ x, const float* __restrict__ emb,
                             const float* __restrict__ pos, float* __restrict__ h,
                             short* __restrict__ hb) {
    int t = threadIdx.x;
    int bl = tok_swizzle(blockIdx.x) + (t >> 6);
    int lane = t & 63;
    int xv = x[bl];
    float mf = (xv != 0) ? 1.f : 0.f;
    int l = bl & (L_ - 1);
    float4 e = *(const float4*)&emb[(size_t)xv * C_ + lane * 4];
    float4 p = *(const float4*)&pos[(size_t)l * C_ + lane * 4];
    float4 o;
    o.x = (e.x + p.x * mf) * mf;
    o.y = (e.y + p.y * mf) * mf;
    o.z = (e.z + p.z * mf) * mf;
    o.w = (e.w + p.w * mf) * mf;
    *(float4*)&h[(size_t)bl * C_ + lane * 4] = o;
    size_t hb0 = (size_t)bl * C_ + lane * 4;
    short4v hv4;
    hv4.x = f2bf(o.x); hv4.y = f2bf(o.y); hv4.z = f2bf(o.z); hv4.w = f2bf(o.w);
    *(short4v*)&hb[hb0] = hv4;
}

// ---------------- weight prep ----------------
__global__ void f2bf_kernel(const float* __restrict__ s, short* __restrict__ d, int n) {
    int i = blockIdx.x * 256 + threadIdx.x;
    if (i < n) d[i] = f2bf(s[i]);
}

// W2cat[l][512][256]: rows 0..255 = gpW[l], 256..511 = gfW[l]
__global__ void prep_w2(const float* __restrict__ gpW, const float* __restrict__ gfW,
                        short* __restrict__ W2) {
    int i = blockIdx.x * 256 + threadIdx.x;
    if (i >= 3 * 512 * 256) return;
    int k = i & 255, r = (i >> 8) & 511, l = i >> 17;
    float v = (r < 256) ? gpW[((size_t)l * 256 + r) * 256 + k]
                        : gfW[((size_t)l * 256 + (r - 256)) * 256 + k];
    W2[i] = f2bf(v);
}

// Asd[l][128][512]: n<16 encodes (type,dir,head): n = type*8 + dir*4 + h.
__global__ void prep_asd(const float* __restrict__ gpas, const float* __restrict__ gpad,
                         const float* __restrict__ gfas, const float* __restrict__ gfad,
                         short* __restrict__ Asd) {
    int i = blockIdx.x * 256 + threadIdx.x;
    if (i >= 3 * 128 * 512) return;
    int k = i & 511, n = (i >> 9) & 127, l = i >> 16;
    float v = 0.f;
    if (n < 16) {
        int type = n >> 3;          // 0 = src(s), 1 = dst(d)
        int dir = (n >> 2) & 1;     // 0 = past, 1 = future
        int hh = n & 3;
        int kk = k - dir * 256;
        if (kk >= 0 && kk < 256 && (kk >> 6) == hh) {
            const float* a = type ? (dir ? gfad : gpad) : (dir ? gfas : gpas);
            v = a[l * 256 + kk];
        }
    }
    Asd[i] = f2bf(v);
}

// Interleaved GRU weights: Bc[l][n'][512], n' = 4*ch + g, g in {0:r,1:z,2:i,3:n}.
//   g=0/1: [Wih[g*256+ch] | Whh[g*256+ch]]; g=2: [Wih[512+ch] | 0]; g=3: [0 | Whh[512+ch]]
__global__ void prep_gru_i(const float* __restrict__ Wih, const float* __restrict__ Whh,
                           short* __restrict__ Bc) {
    int i = blockIdx.x * 256 + threadIdx.x;
    if (i >= 3 * 1024 * 512) return;
    int k = i & 511, np = (i >> 9) & 1023, l = i >> 19;
    int ch = np >> 2, g = np & 3;
    float v = 0.f;
    if (g < 2) {
        v = (k < 256) ? Wih[((size_t)l * 768 + g * 256 + ch) * 256 + k]
                      : Whh[((size_t)l * 768 + g * 256 + ch) * 256 + (k - 256)];
    } else if (g == 2) {
        if (k < 256) v = Wih[((size_t)l * 768 + 512 + ch) * 256 + k];
    } else {
        if (k >= 256) v = Whh[((size_t)l * 768 + 512 + ch) * 256 + (k - 256)];
    }
    Bc[i] = f2bf(v);
}

// bias4[l][4*ch+g]
__global__ void prep_bias4(const float* __restrict__ bih, const float* __restrict__ bhh,
                           float* __restrict__ bc) {
    int i = blockIdx.x * 256 + threadIdx.x;
    if (i >= 3 * 1024) return;
    int np = i & 1023, l = i >> 10;
    int ch = np >> 2, g = np & 3;
    float v;
    if (g < 2)       v = bih[l * 768 + g * 256 + ch] + bhh[l * 768 + g * 256 + ch];
    else if (g == 2) v = bih[l * 768 + 512 + ch];
    else             v = bhh[l * 768 + 512 + ch];
    bc[i] = v;
}

// ---------------- bf16 MFMA GEMM: C[M,N] = A[M,K] * B[N,K]^T ----------------
// 1D grid, XCD-sequential: id%8 = XCD = rb%8; (id>>3) cycles col-blocks fastest.
// Operand-swapped MFMA: lane owns 4 consecutive cols of one row (packed stores).
__global__ __launch_bounds__(256) void bgemm(const short* __restrict__ A0,
                                             const short* __restrict__ A1,
                                             const short* __restrict__ Bw,
                                             void* __restrict__ Cout,
                                             const float* __restrict__ bias,
                                             int K, int lda, int ldc, int nstore,
                                             int cbBits, int flags) {
    __shared__ short As[128 * 32];
    __shared__ short Bs[128 * 32];
    const int id = blockIdx.x;
    const int cb = (id >> 3) & ((1 << cbBits) - 1);
    const int rb = (id & 7) + ((id >> (3 + cbBits)) << 3);
    const int tid = threadIdx.x;
    const int wave = tid >> 6, lane = tid & 63;
    const int wm = wave >> 1, wn = wave & 1;
    const size_t arow0 = (size_t)rb * 128;
    const short* Bb = Bw + (size_t)cb * 128 * K;
    floatx4 acc[4][4];   // [nf][mf]
#pragma unroll
    for (int i = 0; i < 4; i++)
#pragma unroll
        for (int j = 0; j < 4; j++) acc[i][j] = (floatx4)0.f;

    const int srow = lane >> 2;
    const int sq = (lane & 3) * 8;
    const int q = lane >> 4, t16 = lane & 15;

    for (int k0 = 0; k0 < K; k0 += 32) {
        bool useA1 = (A1 != nullptr) && (k0 >= 256);
        const short* Abase = useA1 ? (A1 + arow0 * 256 + (k0 - 256))
                                   : (A0 + arow0 * (size_t)lda + k0);
        int astr = useA1 ? 256 : lda;
#pragma unroll
        for (int t = 0; t < 2; ++t) {
            int r = (wave * 2 + t) * 16 + srow;
            gl_lds16(Abase + (size_t)r * astr + sq, &As[r * 32 + sq]);
            gl_lds16(Bb + (size_t)r * K + k0 + sq, &Bs[r * 32 + sq]);
        }
        __syncthreads();
        short8 af[4], bfr[4];
#pragma unroll
        for (int mf = 0; mf < 4; mf++)
            af[mf] = *(const short8*)&As[(wm * 64 + mf * 16 + t16) * 32 + q * 8];
#pragma unroll
        for (int nf = 0; nf < 4; nf++)
            bfr[nf] = *(const short8*)&Bs[(wn * 64 + nf * 16 + t16) * 32 + q * 8];
#pragma unroll
        for (int mf = 0; mf < 4; mf++)
#pragma unroll
            for (int nf = 0; nf < 4; nf++)
                acc[nf][mf] = __builtin_amdgcn_mfma_f32_16x16x32_bf16(
                    bfr[nf], af[mf], acc[nf][mf], 0, 0, 0);
        __syncthreads();
    }

    const int rowbase = rb * 128 + wm * 64;
    const int colbase = cb * 128 + wn * 64;
#pragma unroll
    for (int nf = 0; nf < 4; nf++) {
        int col0 = colbase + nf * 16 + q * 4;
        if (col0 >= nstore) continue;
        float4 bv4 = make_float4(0.f, 0.f, 0.f, 0.f);
        if (flags & GF_BIAS) bv4 = *(const float4*)&bias[col0];
#pragma unroll
        for (int mf = 0; mf < 4; mf++) {
            int row = rowbase + mf * 16 + t16;
            float v0 = acc[nf][mf][0] + bv4.x;
            float v1 = acc[nf][mf][1] + bv4.y;
            float v2 = acc[nf][mf][2] + bv4.z;
            float v3 = acc[nf][mf][3] + bv4.w;
            if (flags & GF_RELU) {
                v0 = fmaxf(v0, 0.f); v1 = fmaxf(v1, 0.f);
                v2 = fmaxf(v2, 0.f); v3 = fmaxf(v3, 0.f);
            }
            size_t base = (size_t)row * ldc + col0;
            if (flags & GF_OBF16) {
                short4v pk;
                pk.x = f2bf(v0); pk.y = f2bf(v1); pk.z = f2bf(v2); pk.w = f2bf(v3);
                *(short4v*)&((short*)Cout)[base] = pk;
            } else {
                float4 pk = make_float4(v0, v1, v2, v3);
                *(float4*)&((float*)Cout)[base] = pk;
            }
        }
    }
}

// ---------------- FUSED GRU GEMM + gates + LayerNorm + mask ----------------
// A = [mmb | hb] (K=512), B = Bc interleaved (N=1024, n'=4*ch+g), bias4.
// Block: 64 rows x 1024 cols via 8 chunk passes of 128 cols; wave tile 64x32
// (acc[nf<2][mf<4], operand-swapped so lane owns one channel's (r,z,i,n)).
// hn2 staged fp32 in LDS (ld 260 to break bank alignment), then LN phase.
__global__ __launch_bounds__(256) void gru_ln_fused(
    const short* __restrict__ mmb, const short* __restrict__ hb_in,
    const short* __restrict__ Bc, const float* __restrict__ bias4,
    float* __restrict__ h, short* __restrict__ hb,
    const int* __restrict__ mask,
    const float* __restrict__ lng, const float* __restrict__ lnb) {
    __shared__ short As[64 * 32];
    __shared__ short Bs[128 * 32];
    __shared__ float hn2s[64 * 260];
    const int rb = blockIdx.x;              // 64-row block, 512 blocks
    const int tid = threadIdx.x;
    const int wave = tid >> 6, lane = tid & 63;
    const int q = lane >> 4, t16 = lane & 15;
    const size_t row0 = (size_t)rb * 64;

    for (int cc = 0; cc < 8; cc++) {
        int chq = cc * 32 + wave * 8 + q;   // channel = chq + nf*4
        // prefetch h_prev for this chunk's channels (overlaps with K-loop)
        float hp[2][4];
#pragma unroll
        for (int nf = 0; nf < 2; nf++)
#pragma unroll
            for (int mf = 0; mf < 4; mf++)
                hp[nf][mf] = h[(row0 + mf * 16 + t16) * 256 + chq + nf * 4];

        floatx4 acc[2][4];
#pragma unroll
        for (int i = 0; i < 2; i++)
#pragma unroll
            for (int j = 0; j < 4; j++) acc[i][j] = (floatx4)0.f;
        const short* Bb = Bc + (size_t)(cc * 128) * 512;

        for (int k0 = 0; k0 < 512; k0 += 32) {
            const short* Ab = (k0 < 256) ? (mmb + row0 * 256 + k0)
                                         : (hb_in + row0 * 256 + (k0 - 256));
            gl_lds16(Ab + (size_t)(tid >> 2) * 256 + (tid & 3) * 8,
                     &As[(tid >> 2) * 32 + (tid & 3) * 8]);
#pragma unroll
            for (int t = 0; t < 2; t++) {
                int idx = tid + t * 256;
                gl_lds16(Bb + (size_t)(idx >> 2) * 512 + k0 + (idx & 3) * 8,
                         &Bs[(idx >> 2) * 32 + (idx & 3) * 8]);
            }
            __syncthreads();
            short8 af[4], bfr[2];
#pragma unroll
            for (int mf = 0; mf < 4; mf++)
                af[mf] = *(const short8*)&As[(mf * 16 + t16) * 32 + q * 8];
#pragma unroll
            for (int nf = 0; nf < 2; nf++)
                bfr[nf] = *(const short8*)&Bs[(wave * 32 + nf * 16 + t16) * 32 + q * 8];
#pragma unroll
            for (int nf = 0; nf < 2; nf++)
#pragma unroll
                for (int mf = 0; mf < 4; mf++)
                    acc[nf][mf] = __builtin_amdgcn_mfma_f32_16x16x32_bf16(
                        bfr[nf], af[mf], acc[nf][mf], 0, 0, 0);
            __syncthreads();
        }
        // chunk epilogue: gates from fp32 accumulators
#pragma unroll
        for (int nf = 0; nf < 2; nf++) {
            int ch = chq + nf * 4;
            float4 bv = *(const float4*)&bias4[ch * 4];
#pragma unroll
            for (int mf = 0; mf < 4; mf++) {
                float r = sigmoidf_(acc[nf][mf][0] + bv.x);
                float z = sigmoidf_(acc[nf][mf][1] + bv.y);
                float nv = tanhf((acc[nf][mf][2] + bv.z) + r * (acc[nf][mf][3] + bv.w));
                float hn2 = (1.f - z) * nv + z * hp[nf][mf];
                hn2s[(mf * 16 + t16) * 260 + ch] = hn2;
            }
        }
    }
    __syncthreads();
    // LN phase: wave handles 16 rows
    for (int rr = 0; rr < 16; rr++) {
        int lrow = wave * 16 + rr;
        int bl = (int)row0 + lrow;
        float4 v4 = *(const float4*)&hn2s[lrow * 260 + lane * 4];
        float s = (v4.x + v4.y) + (v4.z + v4.w);
        float ss = (v4.x * v4.x + v4.y * v4.y) + (v4.z * v4.z + v4.w * v4.w);
#pragma unroll
        for (int off = 32; off; off >>= 1) {
            s += __shfl_xor(s, off);
            ss += __shfl_xor(ss, off);
        }
        float mu = s * (1.f / 256.f);
        float var = ss * (1.f / 256.f) - mu * mu;
        float rstd = rsqrtf(fmaxf(var, 0.f) + 1e-5f);
        float4 lg = *(const float4*)&lng[lane * 4];
        float4 lb = *(const float4*)&lnb[lane * 4];
        float mfv = mask[bl] ? 1.f : 0.f;
        float4 y;
        y.x = ((v4.x - mu) * rstd * lg.x + lb.x) * mfv;
        y.y = ((v4.y - mu) * rstd * lg.y + lb.y) * mfv;
        y.z = ((v4.z - mu) * rstd * lg.z + lb.z) * mfv;
        y.w = ((v4.w - mu) * rstd * lg.w + lb.w) * mfv;
        *(float4*)&h[(size_t)bl * C_ + lane * 4] = y;
        short4v yb;
        yb.x = f2bf(y.x); yb.y = f2bf(y.y); yb.z = f2bf(y.z); yb.w = f2bf(y.w);
        *(short4v*)&hb[(size_t)bl * C_ + lane * 4] = yb;
    }
}

// ---------------- sparse GAT aggregation, vectorized short8, both dirs ----------------
__global__ __launch_bounds__(256) void agg_fused(
    const short* __restrict__ hpb2, const float* __restrict__ S,
    const int* __restrict__ mask, const int* __restrict__ logical,
    const int* __restrict__ pol, const int* __restrict__ nvalid,
    short* __restrict__ m, int dil) {
    int t = threadIdx.x;
    int bl = tok_swizzle(blockIdx.x) + (t >> 6);
    int sub = t & 63;
    int dir = sub >> 5;
    int slot = sub & 31;
    int cb = slot * 8;
    int head = slot >> 3;
    int b = bl >> 9;

    int mi = mask[bl];
    int li = logical[bl];
    int nv = nvalid[b];
    int js[3]; int nn = 0;
    if (mi) {
#pragma unroll
        for (int k = 1; k <= 3; k++) {
            int lj = dir ? (li - k * dil) : (li + k * dil);
            if (lj >= 0 && lj < nv) js[nn++] = pol[b * L_ + lj];
        }
    }
    int sn = dir * 4 + head, dn = 8 + sn;
    float si = S[(size_t)bl * 16 + sn];
    float di = S[(size_t)bl * 16 + dn];
    float e0 = si + di; e0 = e0 > 0.f ? e0 : 0.2f * e0;
    float emax = e0, ev[3];
    for (int k = 0; k < nn; k++) {
        float djv = S[((size_t)(b * L_ + js[k])) * 16 + dn];
        float e = si + djv; e = e > 0.f ? e : 0.2f * e;
        ev[k] = e; emax = fmaxf(emax, e);
    }
    float w0 = expf(e0 - emax), den = w0;
    float wv[3];
    for (int k = 0; k < nn; k++) { wv[k] = expf(ev[k] - emax); den += wv[k]; }
    float rden = 1.f / den;

    size_t base = (size_t)bl * 512 + dir * 256 + cb;
    short8 vself = *(const short8*)&hpb2[base];
    float o[8];
#pragma unroll
    for (int j = 0; j < 8; j++) o[j] = w0 * bf2f(vself[j]);
    for (int k = 0; k < nn; k++) {
        short8 vn = *(const short8*)&hpb2[((size_t)(b * L_ + js[k])) * 512 + dir * 256 + cb];
#pragma unroll
        for (int j = 0; j < 8; j++) o[j] = fmaf(wv[k], bf2f(vn[j]), o[j]);
    }
    short8 ov;
#pragma unroll
    for (int j = 0; j < 8; j++) ov[j] = f2bf(o[j] * rden);
    *(short8*)&m[base] = ov;
}

// ---------------- masked softmax pooling + both heads ----------------
__global__ __launch_bounds__(1024) void pool_head_kernel(
    const float* __restrict__ h, const int* __restrict__ mask,
    const float* __restrict__ pw, const float* __restrict__ pb,
    const float* __restrict__ h0W, const float* __restrict__ h0b,
    const float* __restrict__ h1W, const float* __restrict__ h1b,
    float* __restrict__ out) {
    int b = blockIdx.x;
    int t = threadIdx.x;
    int lane = t & 63, wave = t >> 6;
    __shared__ float sc[L_];
    __shared__ float red[20];
    __shared__ float part[4][C_];
    __shared__ float pooled[C_];

    float4 wv = *(const float4*)&pw[lane * 4];
    for (int l = wave; l < L_; l += 16) {
        float4 hv = *(const float4*)&h[((size_t)b * L_ + l) * C_ + lane * 4];
        float p = hv.x * wv.x + hv.y * wv.y + hv.z * wv.z + hv.w * wv.w;
#pragma unroll
        for (int off = 32; off; off >>= 1) p += __shfl_down(p, off);
        if (lane == 0) sc[l] = mask[b * L_ + l] ? (p + pb[0]) : NEGV;
    }
    __syncthreads();

    float v = (t < L_) ? sc[t] : NEGV;
    float mx = v;
#pragma unroll
    for (int off = 32; off; off >>= 1) mx = fmaxf(mx, __shfl_down(mx, off));
    if (lane == 0) red[wave] = mx;
    __syncthreads();
    if (t == 0) {
        float g = red[0];
        for (int i = 1; i < 16; i++) g = fmaxf(g, red[i]);
        red[16] = g;
    }
    __syncthreads();
    float gmax = red[16];
    float e = (t < L_) ? expf(v - gmax) : 0.f;
    float ssum = e;
#pragma unroll
    for (int off = 32; off; off >>= 1) ssum += __shfl_down(ssum, off);
    if (lane == 0) red[wave] = ssum;
    __syncthreads();
    if (t == 0) {
        float g = 0.f;
        for (int i = 0; i < 16; i++) g += red[i];
        red[17] = 1.f / g;
    }
    __syncthreads();
    if (t < L_) sc[t] = e * red[17];
    __syncthreads();

    int g = t >> 8, c = t & 255;
    const float* hrow = &h[((size_t)b * L_ + g * 128) * C_ + c];
    const float* scg = &sc[g * 128];
    float a0 = 0.f, a1 = 0.f, a2 = 0.f, a3 = 0.f;
    for (int l = 0; l < 128; l += 4) {
        a0 = fmaf(scg[l + 0], hrow[(size_t)(l + 0) * C_], a0);
        a1 = fmaf(scg[l + 1], hrow[(size_t)(l + 1) * C_], a1);
        a2 = fmaf(scg[l + 2], hrow[(size_t)(l + 2) * C_], a2);
        a3 = fmaf(scg[l + 3], hrow[(size_t)(l + 3) * C_], a3);
    }
    part[g][c] = (a0 + a1) + (a2 + a3);
    __syncthreads();
    if (t < C_) pooled[t] = (part[0][t] + part[1][t]) + (part[2][t] + part[3][t]);
    __syncthreads();

    for (int o = wave; o < 70; o += 16) {
        const float* W = (o < 50) ? (h0W + (size_t)o * C_) : (h1W + (size_t)(o - 50) * C_);
        float bb = (o < 50) ? h0b[o] : h1b[o - 50];
        float4 w4 = *(const float4*)&W[lane * 4];
        float4 p4 = *(const float4*)&pooled[lane * 4];
        float s = p4.x * w4.x + p4.y * w4.y + p4.z * w4.z + p4.w * w4.w;
#pragma unroll
        for (int off = 32; off; off >>= 1) s += __shfl_down(s, off);
        if (lane == 0) out[b * 70 + o] = s + bb;
    }
}

extern "C" void kernel_launch(void* const* d_in, const int* in_sizes, int n_in,
                              void* d_out, int out_size, void* d_ws, size_t ws_size,
                              hipStream_t stream) {
    const int*   x    = (const int*)d_in[0];
    const float* emb  = (const float*)d_in[1];
    const float* pos  = (const float*)d_in[2];
    const float* gpW  = (const float*)d_in[3];
    const float* gpas = (const float*)d_in[4];
    const float* gpad = (const float*)d_in[5];
    const float* gfW  = (const float*)d_in[6];
    const float* gfas = (const float*)d_in[7];
    const float* gfad = (const float*)d_in[8];
    const float* msgW = (const float*)d_in[9];
    const float* msgb = (const float*)d_in[10];
    const float* Wih  = (const float*)d_in[11];
    const float* bih  = (const float*)d_in[12];
    const float* Whh  = (const float*)d_in[13];
    const float* bhh  = (const float*)d_in[14];
    const float* lng  = (const float*)d_in[15];
    const float* lnb  = (const float*)d_in[16];
    const float* pw   = (const float*)d_in[17];
    const float* pb   = (const float*)d_in[18];
    const float* h0W  = (const float*)d_in[19];
    const float* h0b  = (const float*)d_in[20];
    const float* h1W  = (const float*)d_in[21];
    const float* h1b  = (const float*)d_in[22];
    float* out = (float*)d_out;

    // Workspace layout, units MW = 1Mi floats = 4 MiB:
    //   h    fp32 [32768, 256] =  8 MW   -> [ 0,  8)
    //   hb   bf16 [32768, 256] =  4 MW   -> [ 8, 12)
    //   mmb  bf16 [32768, 256] =  4 MW   -> [12, 16)   (also Ssd fp32 [32768,16])
    //   hpb2 bf16 [32768, 512] =  8 MW   -> [16, 24)
    //   mb   bf16 [32768, 512] =  8 MW   -> [24, 32)
    //   weights/bias/masks               -> [32, ~33.4)  (no Gb buffer anymore)
    const size_t MW = 1024 * 1024;
    float* ws = (float*)d_ws;
    float* h    = ws;
    short* hb   = (short*)(ws + 8 * MW);
    short* mmb  = (short*)(ws + 12 * MW);
    float* Ssd  = ws + 12 * MW;                          // aliases mmb (timeshared)
    short* hpb2 = (short*)(ws + 16 * MW);
    short* mb   = (short*)(ws + 24 * MW);
    short* W2cat = (short*)(ws + 32 * MW);               // 3*512*256 shorts
    short* msgWb = W2cat + 3 * 512 * 256;                // 3*256*512 shorts
    short* Bcat  = msgWb + 3 * 256 * 512;                // 3*1024*512 shorts (interleaved)
    short* Asd   = Bcat + 3 * 1024 * 512;                // 3*128*512 shorts
    float* bias4 = (float*)(Asd + 3 * 128 * 512);        // 3*1024 floats
    int* mask    = (int*)(bias4 + 3 * 1024);
    int* logical = mask + B_ * L_;
    int* pol     = logical + B_ * L_;
    int* nvalid  = pol + B_ * L_;

    // weight prep
    prep_w2<<<(3 * 512 * 256 + 255) / 256, 256, 0, stream>>>(gpW, gfW, W2cat);
    f2bf_kernel<<<(3 * 256 * 512 + 255) / 256, 256, 0, stream>>>(msgW, msgWb, 3 * 256 * 512);
    prep_gru_i<<<(3 * 1024 * 512 + 255) / 256, 256, 0, stream>>>(Wih, Whh, Bcat);
    prep_asd<<<(3 * 128 * 512 + 255) / 256, 256, 0, stream>>>(gpas, gpad, gfas, gfad, Asd);
    prep_bias4<<<12, 256, 0, stream>>>(bih, bhh, bias4);

    scan_kernel<<<B_, L_, 0, stream>>>(x, mask, logical, pol, nvalid);
    embed_kernel<<<B_ * L_ / 4, 256, 0, stream>>>(x, emb, pos, h, hb);

    const int DILS[LAY] = {1, 2, 4};

    for (int l = 0; l < LAY; l++) {
        int dil = DILS[l];
        // hpb2 = hb @ [gpW;gfW]^T   (N=512 -> CB=4, cbBits=2, bf16 out)
        bgemm<<<256 * 4, 256, 0, stream>>>(hb, nullptr, W2cat + (size_t)l * 512 * 256,
                                           hpb2, nullptr, 256, 256, 512, 512, 2, GF_OBF16);
        // Ssd = hpb2 @ Asd^T   (CB=1, 16 real cols, fp32, ldc=16)
        bgemm<<<256, 256, 0, stream>>>(hpb2, nullptr, Asd + (size_t)l * 128 * 512,
                                       Ssd, nullptr, 512, 512, 16, 16, 0, 0);
        // sparse GAT aggregation, both dirs in one wave, short8-vectorized
        agg_fused<<<8192, 256, 0, stream>>>(hpb2, Ssd, mask, logical, pol, nvalid, mb, dil);
        // mm = relu(m @ msgW^T + msgb) -> bf16  (CB=2, overwrites Ssd region)
        bgemm<<<256 * 2, 256, 0, stream>>>(mb, nullptr, msgWb + (size_t)l * 256 * 512,
                                           mmb, msgb + l * C_, 512, 512, 256, 256, 1,
                                           GF_BIAS | GF_RELU | GF_OBF16);
        // fused: GRU GEMM (N=1024 interleaved) + gates + LayerNorm + mask -> h, hb
        gru_ln_fused<<<512, 256, 0, stream>>>(mmb, hb, Bcat + (size_t)l * 1024 * 512,
                                              bias4 + l * 1024, h, hb, mask,
                                              lng + l * C_, lnb + l * C_);
    }

    pool_head_kernel<<<B_, 1024, 0, stream>>>(h, mask, pw, pb, h0W, h0b, h1W, h1b, out);
}

// Round 11
// 647.649 us; speedup vs baseline: 1.1555x; 1.1555x over previous
//
#include <hip/hip_runtime.h>
#include <math.h>

#define B_ 64
#define L_ 512
#define C_ 256
#define H_ 4
#define LAY 3
#define NEGV -1e9f

#define GF_BIAS  1
#define GF_RELU  2
#define GF_OBF16 4
#define GF_GRU   8

typedef __attribute__((ext_vector_type(8))) short short8;
typedef __attribute__((ext_vector_type(4))) short short4v;
typedef __attribute__((ext_vector_type(4))) float floatx4;

static __device__ __forceinline__ float sigmoidf_(float x) { return 1.f / (1.f + expf(-x)); }

static __device__ __forceinline__ short f2bf(float f) {
    unsigned x = __float_as_uint(f);
    x += 0x7fffu + ((x >> 16) & 1u);       // round-to-nearest-even to bf16
    return (short)(x >> 16);
}
static __device__ __forceinline__ float bf2f(short s) {
    return __uint_as_float(((unsigned)(unsigned short)s) << 16);
}

// XCD-aligned token swizzle for elementwise consumers (matches GEMM rb%8 = XCD).
static __device__ __forceinline__ int tok_swizzle(int blk) {
    int c8 = blk & 7, i = blk >> 3;
    return (c8 + 8 * (i >> 5)) * 128 + (i & 31) * 4;
}

static __device__ __forceinline__ void gl_lds16(const short* g, short* l) {
    __builtin_amdgcn_global_load_lds(
        (const __attribute__((address_space(1))) unsigned int*)g,
        (__attribute__((address_space(3))) unsigned int*)l, 16, 0, 0);
}

// ---------------- mask / logical-position scan + pos_of_logical ----------------
__global__ void scan_kernel(const int* __restrict__ x, int* __restrict__ mask,
                            int* __restrict__ logical, int* __restrict__ pol,
                            int* __restrict__ nvalid) {
    int b = blockIdx.x, t = threadIdx.x;
    __shared__ int s[L_];
    int m = (x[b * L_ + t] != 0) ? 1 : 0;
    s[t] = m;
    __syncthreads();
    for (int off = 1; off < L_; off <<= 1) {
        int v = (t >= off) ? s[t - off] : 0;
        __syncthreads();
        s[t] += v;
        __syncthreads();
    }
    int cum = s[t];
    int lg = cum - 1; if (lg < 0) lg = 0;
    mask[b * L_ + t] = m;
    logical[b * L_ + t] = lg;
    if (m) pol[b * L_ + lg] = t;
    if (t == L_ - 1) nvalid[b] = cum;
}

// ---------------- hb = bf16((emb[x] + pos*mf)*mf) ----------------
__global__ void embed_kernel(const int* __restrict__ x, const float* __restrict__ emb,
                             const float* __restrict__ pos, short* __restrict__ hb) {
    int t = threadIdx.x;
    int bl = tok_swizzle(blockIdx.x) + (t >> 6);
    int lane = t & 63;
    int xv = x[bl];
    float mf = (xv != 0) ? 1.f : 0.f;
    int l = bl & (L_ - 1);
    float4 e = *(const float4*)&emb[(size_t)xv * C_ + lane * 4];
    float4 p = *(const float4*)&pos[(size_t)l * C_ + lane * 4];
    short4v hv4;
    hv4.x = f2bf((e.x + p.x * mf) * mf);
    hv4.y = f2bf((e.y + p.y * mf) * mf);
    hv4.z = f2bf((e.z + p.z * mf) * mf);
    hv4.w = f2bf((e.w + p.w * mf) * mf);
    *(short4v*)&hb[(size_t)bl * C_ + lane * 4] = hv4;
}

// ---------------- weight prep ----------------
__global__ void f2bf_kernel(const float* __restrict__ s, short* __restrict__ d, int n) {
    int i = blockIdx.x * 256 + threadIdx.x;
    if (i < n) d[i] = f2bf(s[i]);
}

// W2cat[l][512][256]: rows 0..255 = gpW[l], 256..511 = gfW[l]
__global__ void prep_w2(const float* __restrict__ gpW, const float* __restrict__ gfW,
                        short* __restrict__ W2) {
    int i = blockIdx.x * 256 + threadIdx.x;
    if (i >= 3 * 512 * 256) return;
    int k = i & 255, r = (i >> 8) & 511, l = i >> 17;
    float v = (r < 256) ? gpW[((size_t)l * 256 + r) * 256 + k]
                        : gfW[((size_t)l * 256 + (r - 256)) * 256 + k];
    W2[i] = f2bf(v);
}

// Asd[l][128][512]: n<16 encodes (type,dir,head): n = type*8 + dir*4 + h.
__global__ void prep_asd(const float* __restrict__ gpas, const float* __restrict__ gpad,
                         const float* __restrict__ gfas, const float* __restrict__ gfad,
                         short* __restrict__ Asd) {
    int i = blockIdx.x * 256 + threadIdx.x;
    if (i >= 3 * 128 * 512) return;
    int k = i & 511, n = (i >> 9) & 127, l = i >> 16;
    float v = 0.f;
    if (n < 16) {
        int type = n >> 3;          // 0 = src(s), 1 = dst(d)
        int dir = (n >> 2) & 1;     // 0 = past, 1 = future
        int hh = n & 3;
        int kk = k - dir * 256;
        if (kk >= 0 && kk < 256 && (kk >> 6) == hh) {
            const float* a = type ? (dir ? gfad : gpad) : (dir ? gfas : gpas);
            v = a[l * 256 + kk];
        }
    }
    Asd[i] = f2bf(v);
}

// Interleaved GRU weights: Bc[l][n'][512], n' = 4*ch + g, g in {0:r,1:z,2:i,3:n}.
//   g=0/1: [Wih[g*256+ch] | Whh[g*256+ch]]; g=2: [Wih[512+ch] | 0]; g=3: [0 | Whh[512+ch]]
__global__ void prep_gru_i(const float* __restrict__ Wih, const float* __restrict__ Whh,
                           short* __restrict__ Bc) {
    int i = blockIdx.x * 256 + threadIdx.x;
    if (i >= 3 * 1024 * 512) return;
    int k = i & 511, np = (i >> 9) & 1023, l = i >> 19;
    int ch = np >> 2, g = np & 3;
    float v = 0.f;
    if (g < 2) {
        v = (k < 256) ? Wih[((size_t)l * 768 + g * 256 + ch) * 256 + k]
                      : Whh[((size_t)l * 768 + g * 256 + ch) * 256 + (k - 256)];
    } else if (g == 2) {
        if (k < 256) v = Wih[((size_t)l * 768 + 512 + ch) * 256 + k];
    } else {
        if (k >= 256) v = Whh[((size_t)l * 768 + 512 + ch) * 256 + (k - 256)];
    }
    Bc[i] = f2bf(v);
}

// bias4[l][4*ch+g]
__global__ void prep_bias4(const float* __restrict__ bih, const float* __restrict__ bhh,
                           float* __restrict__ bc) {
    int i = blockIdx.x * 256 + threadIdx.x;
    if (i >= 3 * 1024) return;
    int np = i & 1023, l = i >> 10;
    int ch = np >> 2, g = np & 3;
    float v;
    if (g < 2)       v = bih[l * 768 + g * 256 + ch] + bhh[l * 768 + g * 256 + ch];
    else if (g == 2) v = bih[l * 768 + 512 + ch];
    else             v = bhh[l * 768 + 512 + ch];
    bc[i] = v;
}

// ---------------- bf16 MFMA GEMM: C[M,N] = A[M,K] * B[N,K]^T ----------------
// 1D grid, XCD-sequential: id%8 = XCD = rb%8; (id>>3) cycles col-blocks fastest.
// Operand-swapped MFMA: lane owns 4 consecutive cols of one row (packed stores).
// GF_GRU: interleaved-B epilogue -> lane's float4 = (r,z,i,n) preacts of one
// channel; computes hn2 = (1-z)*tanh(i + sig(r)*n) + sig(z)*h_prev, stores bf16
// to Cout[row*256+ch].
__global__ __launch_bounds__(256) void bgemm(const short* __restrict__ A0,
                                             const short* __restrict__ A1,
                                             const short* __restrict__ Bw,
                                             void* __restrict__ Cout,
                                             const float* __restrict__ bias,
                                             const short* __restrict__ hprev,
                                             int K, int lda, int ldc, int nstore,
                                             int cbBits, int flags) {
    __shared__ short As[128 * 32];
    __shared__ short Bs[128 * 32];
    const int id = blockIdx.x;
    const int cb = (id >> 3) & ((1 << cbBits) - 1);
    const int rb = (id & 7) + ((id >> (3 + cbBits)) << 3);
    const int tid = threadIdx.x;
    const int wave = tid >> 6, lane = tid & 63;
    const int wm = wave >> 1, wn = wave & 1;
    const size_t arow0 = (size_t)rb * 128;
    const short* Bb = Bw + (size_t)cb * 128 * K;
    floatx4 acc[4][4];   // [nf][mf]
#pragma unroll
    for (int i = 0; i < 4; i++)
#pragma unroll
        for (int j = 0; j < 4; j++) acc[i][j] = (floatx4)0.f;

    const int srow = lane >> 2;
    const int sq = (lane & 3) * 8;
    const int q = lane >> 4, t16 = lane & 15;

    for (int k0 = 0; k0 < K; k0 += 32) {
        bool useA1 = (A1 != nullptr) && (k0 >= 256);
        const short* Abase = useA1 ? (A1 + arow0 * 256 + (k0 - 256))
                                   : (A0 + arow0 * (size_t)lda + k0);
        int astr = useA1 ? 256 : lda;
#pragma unroll
        for (int t = 0; t < 2; ++t) {
            int r = (wave * 2 + t) * 16 + srow;
            gl_lds16(Abase + (size_t)r * astr + sq, &As[r * 32 + sq]);
            gl_lds16(Bb + (size_t)r * K + k0 + sq, &Bs[r * 32 + sq]);
        }
        __syncthreads();
        short8 af[4], bfr[4];
#pragma unroll
        for (int mf = 0; mf < 4; mf++)
            af[mf] = *(const short8*)&As[(wm * 64 + mf * 16 + t16) * 32 + q * 8];
#pragma unroll
        for (int nf = 0; nf < 4; nf++)
            bfr[nf] = *(const short8*)&Bs[(wn * 64 + nf * 16 + t16) * 32 + q * 8];
#pragma unroll
        for (int mf = 0; mf < 4; mf++)
#pragma unroll
            for (int nf = 0; nf < 4; nf++)
                acc[nf][mf] = __builtin_amdgcn_mfma_f32_16x16x32_bf16(
                    bfr[nf], af[mf], acc[nf][mf], 0, 0, 0);
        __syncthreads();
    }

    const int rowbase = rb * 128 + wm * 64;
    const int colbase = cb * 128 + wn * 64;
#pragma unroll
    for (int nf = 0; nf < 4; nf++) {
        int col0 = colbase + nf * 16 + q * 4;
        if (col0 >= nstore) continue;
        float4 bv4 = make_float4(0.f, 0.f, 0.f, 0.f);
        if (flags & (GF_BIAS | GF_GRU)) bv4 = *(const float4*)&bias[col0];
        if (flags & GF_GRU) {
            int ch = col0 >> 2;
#pragma unroll
            for (int mf = 0; mf < 4; mf++) {
                int row = rowbase + mf * 16 + t16;
                float r = sigmoidf_(acc[nf][mf][0] + bv4.x);
                float z = sigmoidf_(acc[nf][mf][1] + bv4.y);
                float nv = tanhf((acc[nf][mf][2] + bv4.z) + r * (acc[nf][mf][3] + bv4.w));
                float hp = bf2f(hprev[(size_t)row * 256 + ch]);
                float hn2 = (1.f - z) * nv + z * hp;
                ((short*)Cout)[(size_t)row * 256 + ch] = f2bf(hn2);
            }
            continue;
        }
#pragma unroll
        for (int mf = 0; mf < 4; mf++) {
            int row = rowbase + mf * 16 + t16;
            float v0 = acc[nf][mf][0] + bv4.x;
            float v1 = acc[nf][mf][1] + bv4.y;
            float v2 = acc[nf][mf][2] + bv4.z;
            float v3 = acc[nf][mf][3] + bv4.w;
            if (flags & GF_RELU) {
                v0 = fmaxf(v0, 0.f); v1 = fmaxf(v1, 0.f);
                v2 = fmaxf(v2, 0.f); v3 = fmaxf(v3, 0.f);
            }
            size_t base = (size_t)row * ldc + col0;
            if (flags & GF_OBF16) {
                short4v pk;
                pk.x = f2bf(v0); pk.y = f2bf(v1); pk.z = f2bf(v2); pk.w = f2bf(v3);
                *(short4v*)&((short*)Cout)[base] = pk;
            } else {
                float4 pk = make_float4(v0, v1, v2, v3);
                *(float4*)&((float*)Cout)[base] = pk;
            }
        }
    }
}

// ---------------- LayerNorm over hn2 (bf16) + mask -> hb ----------------
__global__ __launch_bounds__(256) void ln_kernel(
    const short* __restrict__ hn2b, short* __restrict__ hb,
    const int* __restrict__ mask,
    const float* __restrict__ lng, const float* __restrict__ lnb) {
    int t = threadIdx.x;
    int bl = tok_swizzle(blockIdx.x) + (t >> 6);
    int lane = t & 63;
    short4v v4 = *(const short4v*)&hn2b[(size_t)bl * C_ + lane * 4];
    float v[4] = {bf2f(v4.x), bf2f(v4.y), bf2f(v4.z), bf2f(v4.w)};
    float s = (v[0] + v[1]) + (v[2] + v[3]);
    float ss = (v[0] * v[0] + v[1] * v[1]) + (v[2] * v[2] + v[3] * v[3]);
#pragma unroll
    for (int off = 32; off; off >>= 1) {
        s += __shfl_xor(s, off);
        ss += __shfl_xor(ss, off);
    }
    float mu = s * (1.f / 256.f);
    float var = ss * (1.f / 256.f) - mu * mu;
    float rstd = rsqrtf(fmaxf(var, 0.f) + 1e-5f);
    float4 lg = *(const float4*)&lng[lane * 4];
    float4 lb = *(const float4*)&lnb[lane * 4];
    float mfv = mask[bl] ? 1.f : 0.f;
    short4v yb;
    yb.x = f2bf(((v[0] - mu) * rstd * lg.x + lb.x) * mfv);
    yb.y = f2bf(((v[1] - mu) * rstd * lg.y + lb.y) * mfv);
    yb.z = f2bf(((v[2] - mu) * rstd * lg.z + lb.z) * mfv);
    yb.w = f2bf(((v[3] - mu) * rstd * lg.w + lb.w) * mfv);
    *(short4v*)&hb[(size_t)bl * C_ + lane * 4] = yb;
}

// ---------------- sparse GAT aggregation, vectorized short8, both dirs ----------------
__global__ __launch_bounds__(256) void agg_fused(
    const short* __restrict__ hpb2, const float* __restrict__ S,
    const int* __restrict__ mask, const int* __restrict__ logical,
    const int* __restrict__ pol, const int* __restrict__ nvalid,
    short* __restrict__ m, int dil) {
    int t = threadIdx.x;
    int bl = tok_swizzle(blockIdx.x) + (t >> 6);
    int sub = t & 63;
    int dir = sub >> 5;
    int slot = sub & 31;
    int cb = slot * 8;
    int head = slot >> 3;
    int b = bl >> 9;

    int mi = mask[bl];
    int li = logical[bl];
    int nv = nvalid[b];
    int js[3]; int nn = 0;
    if (mi) {
#pragma unroll
        for (int k = 1; k <= 3; k++) {
            int lj = dir ? (li - k * dil) : (li + k * dil);
            if (lj >= 0 && lj < nv) js[nn++] = pol[b * L_ + lj];
        }
    }
    int sn = dir * 4 + head, dn = 8 + sn;
    float si = S[(size_t)bl * 16 + sn];
    float di = S[(size_t)bl * 16 + dn];
    float e0 = si + di; e0 = e0 > 0.f ? e0 : 0.2f * e0;
    float emax = e0, ev[3];
    for (int k = 0; k < nn; k++) {
        float djv = S[((size_t)(b * L_ + js[k])) * 16 + dn];
        float e = si + djv; e = e > 0.f ? e : 0.2f * e;
        ev[k] = e; emax = fmaxf(emax, e);
    }
    float w0 = expf(e0 - emax), den = w0;
    float wv[3];
    for (int k = 0; k < nn; k++) { wv[k] = expf(ev[k] - emax); den += wv[k]; }
    float rden = 1.f / den;

    size_t base = (size_t)bl * 512 + dir * 256 + cb;
    short8 vself = *(const short8*)&hpb2[base];
    float o[8];
#pragma unroll
    for (int j = 0; j < 8; j++) o[j] = w0 * bf2f(vself[j]);
    for (int k = 0; k < nn; k++) {
        short8 vn = *(const short8*)&hpb2[((size_t)(b * L_ + js[k])) * 512 + dir * 256 + cb];
#pragma unroll
        for (int j = 0; j < 8; j++) o[j] = fmaf(wv[k], bf2f(vn[j]), o[j]);
    }
    short8 ov;
#pragma unroll
    for (int j = 0; j < 8; j++) ov[j] = f2bf(o[j] * rden);
    *(short8*)&m[base] = ov;
}

// ---------------- masked softmax pooling + both heads (bf16 h) ----------------
__global__ __launch_bounds__(1024) void pool_head_kernel(
    const short* __restrict__ hb, const int* __restrict__ mask,
    const float* __restrict__ pw, const float* __restrict__ pb,
    const float* __restrict__ h0W, const float* __restrict__ h0b,
    const float* __restrict__ h1W, const float* __restrict__ h1b,
    float* __restrict__ out) {
    int b = blockIdx.x;
    int t = threadIdx.x;
    int lane = t & 63, wave = t >> 6;
    __shared__ float sc[L_];
    __shared__ float red[20];
    __shared__ float part[4][C_];
    __shared__ float pooled[C_];

    float4 wv = *(const float4*)&pw[lane * 4];
    for (int l = wave; l < L_; l += 16) {
        short4v hv = *(const short4v*)&hb[((size_t)b * L_ + l) * C_ + lane * 4];
        float p = bf2f(hv.x) * wv.x + bf2f(hv.y) * wv.y
                + bf2f(hv.z) * wv.z + bf2f(hv.w) * wv.w;
#pragma unroll
        for (int off = 32; off; off >>= 1) p += __shfl_down(p, off);
        if (lane == 0) sc[l] = mask[b * L_ + l] ? (p + pb[0]) : NEGV;
    }
    __syncthreads();

    float v = (t < L_) ? sc[t] : NEGV;
    float mx = v;
#pragma unroll
    for (int off = 32; off; off >>= 1) mx = fmaxf(mx, __shfl_down(mx, off));
    if (lane == 0) red[wave] = mx;
    __syncthreads();
    if (t == 0) {
        float g = red[0];
        for (int i = 1; i < 16; i++) g = fmaxf(g, red[i]);
        red[16] = g;
    }
    __syncthreads();
    float gmax = red[16];
    float e = (t < L_) ? expf(v - gmax) : 0.f;
    float ssum = e;
#pragma unroll
    for (int off = 32; off; off >>= 1) ssum += __shfl_down(ssum, off);
    if (lane == 0) red[wave] = ssum;
    __syncthreads();
    if (t == 0) {
        float g = 0.f;
        for (int i = 0; i < 16; i++) g += red[i];
        red[17] = 1.f / g;
    }
    __syncthreads();
    if (t < L_) sc[t] = e * red[17];
    __syncthreads();

    int g = t >> 8, c = t & 255;
    const short* hrow = &hb[((size_t)b * L_ + g * 128) * C_ + c];
    const float* scg = &sc[g * 128];
    float a0 = 0.f, a1 = 0.f, a2 = 0.f, a3 = 0.f;
    for (int l = 0; l < 128; l += 4) {
        a0 = fmaf(scg[l + 0], bf2f(hrow[(size_t)(l + 0) * C_]), a0);
        a1 = fmaf(scg[l + 1], bf2f(hrow[(size_t)(l + 1) * C_]), a1);
        a2 = fmaf(scg[l + 2], bf2f(hrow[(size_t)(l + 2) * C_]), a2);
        a3 = fmaf(scg[l + 3], bf2f(hrow[(size_t)(l + 3) * C_]), a3);
    }
    part[g][c] = (a0 + a1) + (a2 + a3);
    __syncthreads();
    if (t < C_) pooled[t] = (part[0][t] + part[1][t]) + (part[2][t] + part[3][t]);
    __syncthreads();

    for (int o = wave; o < 70; o += 16) {
        const float* W = (o < 50) ? (h0W + (size_t)o * C_) : (h1W + (size_t)(o - 50) * C_);
        float bb = (o < 50) ? h0b[o] : h1b[o - 50];
        float4 w4 = *(const float4*)&W[lane * 4];
        float4 p4 = *(const float4*)&pooled[lane * 4];
        float s = p4.x * w4.x + p4.y * w4.y + p4.z * w4.z + p4.w * w4.w;
#pragma unroll
        for (int off = 32; off; off >>= 1) s += __shfl_down(s, off);
        if (lane == 0) out[b * 70 + o] = s + bb;
    }
}

extern "C" void kernel_launch(void* const* d_in, const int* in_sizes, int n_in,
                              void* d_out, int out_size, void* d_ws, size_t ws_size,
                              hipStream_t stream) {
    const int*   x    = (const int*)d_in[0];
    const float* emb  = (const float*)d_in[1];
    const float* pos  = (const float*)d_in[2];
    const float* gpW  = (const float*)d_in[3];
    const float* gpas = (const float*)d_in[4];
    const float* gpad = (const float*)d_in[5];
    const float* gfW  = (const float*)d_in[6];
    const float* gfas = (const float*)d_in[7];
    const float* gfad = (const float*)d_in[8];
    const float* msgW = (const float*)d_in[9];
    const float* msgb = (const float*)d_in[10];
    const float* Wih  = (const float*)d_in[11];
    const float* bih  = (const float*)d_in[12];
    const float* Whh  = (const float*)d_in[13];
    const float* bhh  = (const float*)d_in[14];
    const float* lng  = (const float*)d_in[15];
    const float* lnb  = (const float*)d_in[16];
    const float* pw   = (const float*)d_in[17];
    const float* pb   = (const float*)d_in[18];
    const float* h0W  = (const float*)d_in[19];
    const float* h0b  = (const float*)d_in[20];
    const float* h1W  = (const float*)d_in[21];
    const float* h1b  = (const float*)d_in[22];
    float* out = (float*)d_out;

    // Workspace layout, units MW = 1Mi floats = 4 MiB:
    //   hn2b bf16 [32768, 256] =  4 MW   -> [ 0,  4)
    //   hb   bf16 [32768, 256] =  4 MW   -> [ 8, 12)
    //   mmb  bf16 [32768, 256] =  4 MW   -> [12, 16)   (also Ssd fp32 [32768,16])
    //   hpb2 bf16 [32768, 512] =  8 MW   -> [16, 24)
    //   mb   bf16 [32768, 512] =  8 MW   -> [24, 32)
    //   weights/bias/masks               -> [32, ~33.4)
    // Per-layer: proj(hb->hpb2); sd(hpb2->Ssd); agg(hpb2,Ssd->mb); msg(mb->mmb);
    // gru+gates(mmb,hb->hn2b); ln(hn2b->hb).
    const size_t MW = 1024 * 1024;
    float* ws = (float*)d_ws;
    short* hn2b = (short*)ws;
    short* hb   = (short*)(ws + 8 * MW);
    short* mmb  = (short*)(ws + 12 * MW);
    float* Ssd  = ws + 12 * MW;                          // aliases mmb (timeshared)
    short* hpb2 = (short*)(ws + 16 * MW);
    short* mb   = (short*)(ws + 24 * MW);
    short* W2cat = (short*)(ws + 32 * MW);               // 3*512*256 shorts
    short* msgWb = W2cat + 3 * 512 * 256;                // 3*256*512 shorts
    short* Bcat  = msgWb + 3 * 256 * 512;                // 3*1024*512 shorts (interleaved)
    short* Asd   = Bcat + 3 * 1024 * 512;                // 3*128*512 shorts
    float* bias4 = (float*)(Asd + 3 * 128 * 512);        // 3*1024 floats
    int* mask    = (int*)(bias4 + 3 * 1024);
    int* logical = mask + B_ * L_;
    int* pol     = logical + B_ * L_;
    int* nvalid  = pol + B_ * L_;

    // weight prep
    prep_w2<<<(3 * 512 * 256 + 255) / 256, 256, 0, stream>>>(gpW, gfW, W2cat);
    f2bf_kernel<<<(3 * 256 * 512 + 255) / 256, 256, 0, stream>>>(msgW, msgWb, 3 * 256 * 512);
    prep_gru_i<<<(3 * 1024 * 512 + 255) / 256, 256, 0, stream>>>(Wih, Whh, Bcat);
    prep_asd<<<(3 * 128 * 512 + 255) / 256, 256, 0, stream>>>(gpas, gpad, gfas, gfad, Asd);
    prep_bias4<<<12, 256, 0, stream>>>(bih, bhh, bias4);

    scan_kernel<<<B_, L_, 0, stream>>>(x, mask, logical, pol, nvalid);
    embed_kernel<<<B_ * L_ / 4, 256, 0, stream>>>(x, emb, pos, hb);

    const int DILS[LAY] = {1, 2, 4};

    for (int l = 0; l < LAY; l++) {
        int dil = DILS[l];
        // hpb2 = hb @ [gpW;gfW]^T   (N=512 -> CB=4, cbBits=2, bf16 out)
        bgemm<<<256 * 4, 256, 0, stream>>>(hb, nullptr, W2cat + (size_t)l * 512 * 256,
                                           hpb2, nullptr, nullptr,
                                           256, 256, 512, 512, 2, GF_OBF16);
        // Ssd = hpb2 @ Asd^T   (CB=1, 16 real cols, fp32, ldc=16)
        bgemm<<<256, 256, 0, stream>>>(hpb2, nullptr, Asd + (size_t)l * 128 * 512,
                                       Ssd, nullptr, nullptr,
                                       512, 512, 16, 16, 0, 0);
        // sparse GAT aggregation, both dirs in one wave, short8-vectorized
        agg_fused<<<8192, 256, 0, stream>>>(hpb2, Ssd, mask, logical, pol, nvalid, mb, dil);
        // mm = relu(m @ msgW^T + msgb) -> bf16  (CB=2, overwrites Ssd region)
        bgemm<<<256 * 2, 256, 0, stream>>>(mb, nullptr, msgWb + (size_t)l * 256 * 512,
                                           mmb, msgb + l * C_, nullptr,
                                           512, 512, 256, 256, 1,
                                           GF_BIAS | GF_RELU | GF_OBF16);
        // GRU GEMM (N=1024 interleaved) + gate epilogue -> hn2b bf16 [32768,256]
        bgemm<<<256 * 8, 256, 0, stream>>>(mmb, hb, Bcat + (size_t)l * 1024 * 512,
                                           hn2b, bias4 + l * 1024, hb,
                                           512, 256, 256, 1024, 3, GF_GRU);
        // LayerNorm + mask -> hb
        ln_kernel<<<8192, 256, 0, stream>>>(hn2b, hb, mask, lng + l * C_, lnb + l * C_);
    }

    pool_head_kernel<<<B_, 1024, 0, stream>>>(hb, mask, pw, pb, h0W, h0b, h1W, h1b, out);
}